// Round 17
// baseline (164.290 us; speedup 1.0000x reference)
//
#include <hip/hip_runtime.h>

typedef unsigned int u32;
typedef int i32x4 __attribute__((ext_vector_type(4)));
typedef int i32x16 __attribute__((ext_vector_type(16)));

// ws layout (bytes):
//   0        amax (float)
//   64       part: 256 partial maxima
//   2048     Wq2: fragment-major i8, 768 KB  (nt*24576 + ks*1024 + col*32 + kb)
//   790528   bucket u32[65536]               (256 KB)
//   1052672  psqt  f32[65536]                (256 KB)
//   1314816  partial f32[8][65536]           (2 MB)
//   3411968  masks u32[65536][2][12]         (6 MB)   96 B per row
#define WQ_OFF    2048
#define BKT_OFF   790528
#define PSQ_OFF   1052672
#define PAR_OFF   1314816
#define MSK_OFF   3411968

#define PKB(f) ((__float_as_uint(f.x) >> 29)         |                      \
                ((__float_as_uint(f.y) >> 29) << 8)  |                      \
                ((__float_as_uint(f.z) >> 29) << 16) |                      \
                ((__float_as_uint(f.w) >> 29) << 24))
#define DOT4(f, p) ps = fmaf(f.x, p.x, ps); ps = fmaf(f.y, p.y, ps);        \
                   ps = fmaf(f.z, p.z, ps); ps = fmaf(f.w, p.w, ps);

// ---------------------------------------------------------------------------
// absmax two-stage tree (no atomics)  [validated r3+]
// ---------------------------------------------------------------------------
__global__ __launch_bounds__(256) void amax_stage1(const float* __restrict__ W,
                                                   float* __restrict__ part) {
    int t = blockIdx.x * 256 + threadIdx.x;
    float v = 0.0f;
#pragma unroll
    for (int k = 0; k < 12; ++k) v = fmaxf(v, fabsf(W[t + (k << 16)]));
#pragma unroll
    for (int d = 32; d >= 1; d >>= 1) v = fmaxf(v, __shfl_xor(v, d));
    __shared__ float sm[4];
    if ((threadIdx.x & 63) == 0) sm[threadIdx.x >> 6] = v;
    __syncthreads();
    if (threadIdx.x == 0)
        part[blockIdx.x] = fmaxf(fmaxf(sm[0], sm[1]), fmaxf(sm[2], sm[3]));
}

__global__ __launch_bounds__(256) void amax_stage2(const float* __restrict__ part,
                                                   float* __restrict__ amax) {
    float v = part[threadIdx.x];
#pragma unroll
    for (int d = 32; d >= 1; d >>= 1) v = fmaxf(v, __shfl_xor(v, d));
    __shared__ float sm[4];
    if ((threadIdx.x & 63) == 0) sm[threadIdx.x >> 6] = v;
    __syncthreads();
    if (threadIdx.x == 0)
        amax[0] = fmaxf(fmaxf(sm[0], sm[1]), fmaxf(sm[2], sm[3]));
}

// ---------------------------------------------------------------------------
// quantize W_in [1024][768] f32 -> Wq2 fragment-major i8  [validated r9-r15]
// ---------------------------------------------------------------------------
__global__ __launch_bounds__(192) void quant_k(const float* __restrict__ W,
                                               const float* __restrict__ amax,
                                               u32* __restrict__ Wq4) {
    const int n = blockIdx.x, kd = threadIdx.x;     // kd: dword index 0..191
    float s = 127.0f / amax[0];
    float4 v = ((const float4*)(W + n * 768))[kd];
    int a0 = (int)rintf(v.x * s), a1 = (int)rintf(v.y * s);
    int a2 = (int)rintf(v.z * s), a3 = (int)rintf(v.w * s);
    u32 wq = (u32)(a0 & 0xFF) | ((u32)(a1 & 0xFF) << 8) |
             ((u32)(a2 & 0xFF) << 16) | ((u32)(a3 & 0xFF) << 24);
    const int nt = n >> 5, c = n & 31, kc = kd >> 3, kb4 = kd & 7;
    Wq4[nt * 6144 + kc * 256 + c * 8 + kb4] = wq;
}

// ---------------------------------------------------------------------------
// pack_k: x -> bitmasks + bucket + psqt. One thread per quarter-row
// (262144 threads). Fully coalesced (4 threads cover a 3 KB row linearly).
// masks[row][hi][d]: d-th dword = m16(ks=2d) | m16(ks=2d+1)<<16, where
// m16 bit j = x[row][ks*32 + hi*16 + j]  (matches the r12-validated pack).
// ---------------------------------------------------------------------------
__global__ __launch_bounds__(256) void pack_k(const float* __restrict__ x,
                                              const float* __restrict__ W_psqt,
                                              u32* __restrict__ masks,
                                              u32* __restrict__ bucket,
                                              float* __restrict__ psqt) {
    const int g = blockIdx.x * 256 + threadIdx.x;   // 0..262143
    const int row = g >> 2, qq = g & 3;             // quarter = 192 k
    const float4* xr = (const float4*)(x + (size_t)row * 768) + qq * 48;
    const float4* pw = (const float4*)W_psqt + qq * 48;

    u32 csum = 0;
    float ps = 0.0f;
    u32 mout[2][3];
#pragma unroll
    for (int jj = 0; jj < 6; ++jj) {                // local ks
#pragma unroll
        for (int hi = 0; hi < 2; ++hi) {
            int fi = jj * 8 + hi * 4;
            float4 f0 = xr[fi + 0], f1 = xr[fi + 1];
            float4 f2 = xr[fi + 2], f3 = xr[fi + 3];
            float4 p0 = pw[fi + 0], p1 = pw[fi + 1];
            float4 p2 = pw[fi + 2], p3 = pw[fi + 3];
            u32 d0 = PKB(f0), d1 = PKB(f1), d2 = PKB(f2), d3 = PKB(f3);
            csum += d0 + d1 + d2 + d3;              // byte sums <= 24
            DOT4(f0, p0) DOT4(f1, p1) DOT4(f2, p2) DOT4(f3, p3)
            u32 m16 = ((d0 * 0x01020408u) >> 24)
                    | (((d1 * 0x01020408u) >> 24) << 4)
                    | (((d2 * 0x01020408u) >> 24) << 8)
                    | (((d3 * 0x01020408u) >> 24) << 12);
            if (jj & 1) mout[hi][jj >> 1] |= m16 << 16;
            else        mout[hi][jj >> 1]  = m16;
        }
    }
    int cnt = (csum & 0xFF) + ((csum >> 8) & 0xFF) +
              ((csum >> 16) & 0xFF) + (csum >> 24);
    cnt += __shfl_xor(cnt, 1); cnt += __shfl_xor(cnt, 2);
    ps  += __shfl_xor(ps, 1);  ps  += __shfl_xor(ps, 2);

    u32* mp = masks + (size_t)row * 24 + qq * 3;
#pragma unroll
    for (int hi = 0; hi < 2; ++hi) {
        mp[hi * 12 + 0] = mout[hi][0];
        mp[hi * 12 + 1] = mout[hi][1];
        mp[hi * 12 + 2] = mout[hi][2];
    }
    if (qq == 0) {
        bucket[row] = (u32)((cnt - 1) >> 2);
        psqt[row] = ps;
    }
}

// ---------------------------------------------------------------------------
// gemm_k: B-in-registers, zero LDS in the loop, zero in-loop barriers.
// 256 thr = 4 waves; wave w owns n-tile nt = band*4+w (32 cols) x full K:
// B = 24 x i32x4 = 96 VGPRs loaded once from L2. Block covers 512 rows
// (16 row-groups of 32). Per row-group: Ab (12 dwords, prefetched one
// group ahead from masks) -> 24 expand+MFMA -> fused epilogue ->
// shfl-reduce -> LDS comb (no barrier until the very end).
// Per-band partial output (deterministic combine in finish_k).
// ---------------------------------------------------------------------------
__global__ __launch_bounds__(256)
__attribute__((amdgpu_waves_per_eu(2, 2)))
void gemm_k(const signed char* __restrict__ Wq2,
            const u32* __restrict__ masks,
            const u32* __restrict__ bucket,
            const float* __restrict__ amax,
            const float* __restrict__ b_in,
            const float* __restrict__ W_h,
            float* __restrict__ partial) {
    __shared__ float comb[512][4];

    const int t = threadIdx.x, l = t & 63, w = t >> 6;
    const int cl = l & 31, hi = l >> 5;
    const int band = blockIdx.x & 7, chunk = blockIdx.x >> 3;
    const int nt = band * 4 + w;                    // this wave's n-tile
    const int rowbase = chunk << 9;                 // *512

    // ---- B: 24 fragments, persistent in registers ----------------------
    i32x4 Breg[24];
    {
        const i32x4* bp = (const i32x4*)(Wq2 + (size_t)nt * 24576
                                         + (cl << 5) + (hi << 4));
#pragma unroll
        for (int ks = 0; ks < 24; ++ks) Breg[ks] = bp[ks * 64];
    }

    const float sc = amax[0] * (1.0f / 127.0f);
    const float bi = b_in[(nt << 5) + cl];
    const float* whc = W_h + (nt << 5) + cl;

    const u32* mp = masks + (size_t)(rowbase + cl) * 24 + hi * 12;
    uint4 nA0 = *(const uint4*)(mp);
    uint4 nA1 = *(const uint4*)(mp + 4);
    uint4 nA2 = *(const uint4*)(mp + 8);

    for (int rg = 0; rg < 16; ++rg) {
        uint4 A0 = nA0, A1 = nA1, A2 = nA2;
        if (rg < 15) {                              // prefetch next group
            const u32* mq = mp + (size_t)(rg + 1) * 768;
            nA0 = *(const uint4*)(mq);
            nA1 = *(const uint4*)(mq + 4);
            nA2 = *(const uint4*)(mq + 8);
        }
        u32 Ab[12] = {A0.x, A0.y, A0.z, A0.w,
                      A1.x, A1.y, A1.z, A1.w,
                      A2.x, A2.y, A2.z, A2.w};

        i32x16 acc = {0,0,0,0,0,0,0,0,0,0,0,0,0,0,0,0};
#pragma unroll
        for (int ks = 0; ks < 24; ++ks) {
            u32 pair = Ab[ks >> 1];                 // static after unroll
            u32 m = (ks & 1) ? (pair >> 16) : (pair & 0xFFFFu);
            i32x4 af;
            af[0] = (int)(((m         & 0xFu) * 0x00204081u) & 0x01010101u);
            af[1] = (int)((((m >> 4)  & 0xFu) * 0x00204081u) & 0x01010101u);
            af[2] = (int)((((m >> 8)  & 0xFu) * 0x00204081u) & 0x01010101u);
            af[3] = (int)((((m >> 12)       ) * 0x00204081u) & 0x01010101u);
            acc = __builtin_amdgcn_mfma_i32_32x32x32_i8(af, Breg[ks], acc,
                                                        0, 0, 0);
        }

        // fused epilogue: h = clip(acc*sc + b_in), dot with bucket head
        float rs[16];
#pragma unroll
        for (int g16 = 0; g16 < 16; ++g16) {
            int er = rowbase + (rg << 5)
                   + (g16 & 3) + ((g16 >> 2) << 3) + (hi << 2);
            int boff = (int)bucket[er] << 10;
            float h = fminf(fmaxf(fmaf((float)acc[g16], sc, bi), 0.f), 1.f);
            rs[g16] = h * whc[boff];
        }
#pragma unroll
        for (int g16 = 0; g16 < 16; ++g16) {
#pragma unroll
            for (int d = 1; d < 32; d <<= 1)
                rs[g16] += __shfl_xor(rs[g16], d);
        }
        if (cl == 0) {
#pragma unroll
            for (int g16 = 0; g16 < 16; ++g16) {
                int er = (rg << 5) + (g16 & 3) + ((g16 >> 2) << 3) + (hi << 2);
                comb[er][w] = rs[g16];
            }
        }
    }
    __syncthreads();                                // the ONLY barrier
#pragma unroll
    for (int r = t; r < 512; r += 256) {
        partial[(size_t)band * 65536 + rowbase + r] =
            comb[r][0] + comb[r][1] + comb[r][2] + comb[r][3];
    }
}

// ---------------------------------------------------------------------------
// finish_k: out = sum of band partials + psqt + b_h[bucket]
// ---------------------------------------------------------------------------
__global__ __launch_bounds__(256) void finish_k(const float* __restrict__ partial,
                                                const float* __restrict__ psqt,
                                                const u32* __restrict__ bucket,
                                                const float* __restrict__ b_h,
                                                float* __restrict__ out) {
    int r = blockIdx.x * 256 + threadIdx.x;
    float s = psqt[r] + b_h[bucket[r]];
#pragma unroll
    for (int b = 0; b < 8; ++b) s += partial[(size_t)b * 65536 + r];
    out[r] = s;
}

extern "C" void kernel_launch(void* const* d_in, const int* in_sizes, int n_in,
                              void* d_out, int out_size, void* d_ws, size_t ws_size,
                              hipStream_t stream) {
    const float* x      = (const float*)d_in[0];
    const float* W_in   = (const float*)d_in[1];
    const float* b_in   = (const float*)d_in[2];
    const float* W_h    = (const float*)d_in[3];
    const float* b_h    = (const float*)d_in[4];
    const float* W_psqt = (const float*)d_in[5];
    float* out = (float*)d_out;

    char* ws = (char*)d_ws;
    float* amax   = (float*)ws;
    float* part   = (float*)(ws + 64);
    u32*   Wq4    = (u32*)(ws + WQ_OFF);
    u32*   bucket = (u32*)(ws + BKT_OFF);
    float* psqt   = (float*)(ws + PSQ_OFF);
    float* partial= (float*)(ws + PAR_OFF);
    u32*   masks  = (u32*)(ws + MSK_OFF);

    amax_stage1<<<256, 256, 0, stream>>>(W_in, part);
    amax_stage2<<<1, 256, 0, stream>>>(part, amax);
    quant_k<<<1024, 192, 0, stream>>>(W_in, amax, Wq4);

    int B = out_size;                   // 65536
    pack_k<<<(B * 4) / 256, 256, 0, stream>>>(x, W_psqt, masks, bucket, psqt);
    gemm_k<<<8 * (B / 512), 256, 0, stream>>>((const signed char*)Wq4, masks,
                                              bucket, amax, b_in, W_h, partial);
    finish_k<<<B / 256, 256, 0, stream>>>(partial, psqt, bucket, b_h, out);
}

// Round 18
// 101.254 us; speedup vs baseline: 1.6226x; 1.6226x over previous
//
#include <hip/hip_runtime.h>

typedef unsigned int u32;
typedef unsigned short u16;
typedef int i32x4 __attribute__((ext_vector_type(4)));
typedef int i32x16 __attribute__((ext_vector_type(16)));

// ws layout (bytes):
//   [0..3]      amax (float)
//   [64..1087]  256 partial maxima (float)
//   [2048..]    Wq2: fragment-major i8 weights, 768 KB:
//               addr = nt*24576 + ks*1024 + col*32 + kb
//               (n = nt*32+col in [0,1024), k = ks*32+kb in [0,768))
#define WQ_OFF 2048

__device__ __forceinline__ void gld16(const void* g, void* l) {
    __builtin_amdgcn_global_load_lds(
        (const __attribute__((address_space(1))) void*)g,
        (__attribute__((address_space(3))) void*)l, 16, 0, 0);
}

// ---------------------------------------------------------------------------
// absmax two-stage tree (no atomics)
// ---------------------------------------------------------------------------
__global__ __launch_bounds__(256) void amax_stage1(const float* __restrict__ W,
                                                   float* __restrict__ part) {
    int t = blockIdx.x * 256 + threadIdx.x;
    float v = 0.0f;
#pragma unroll
    for (int k = 0; k < 12; ++k) v = fmaxf(v, fabsf(W[t + (k << 16)]));
#pragma unroll
    for (int d = 32; d >= 1; d >>= 1) v = fmaxf(v, __shfl_xor(v, d));
    __shared__ float sm[4];
    if ((threadIdx.x & 63) == 0) sm[threadIdx.x >> 6] = v;
    __syncthreads();
    if (threadIdx.x == 0)
        part[blockIdx.x] = fmaxf(fmaxf(sm[0], sm[1]), fmaxf(sm[2], sm[3]));
}

__global__ __launch_bounds__(256) void amax_stage2(const float* __restrict__ part,
                                                   float* __restrict__ amax) {
    float v = part[threadIdx.x];
#pragma unroll
    for (int d = 32; d >= 1; d >>= 1) v = fmaxf(v, __shfl_xor(v, d));
    __shared__ float sm[4];
    if ((threadIdx.x & 63) == 0) sm[threadIdx.x >> 6] = v;
    __syncthreads();
    if (threadIdx.x == 0)
        amax[0] = fmaxf(fmaxf(sm[0], sm[1]), fmaxf(sm[2], sm[3]));
}

// ---------------------------------------------------------------------------
// quantize W_in [1024][768] f32 -> Wq2 fragment-major i8 (validated r9-r17)
// ---------------------------------------------------------------------------
__global__ __launch_bounds__(192) void quant_k(const float* __restrict__ W,
                                               const float* __restrict__ amax,
                                               u32* __restrict__ Wq4) {
    const int n = blockIdx.x, kd = threadIdx.x;     // kd: dword index 0..191
    float s = 127.0f / amax[0];
    float4 v = ((const float4*)(W + n * 768))[kd];
    int a0 = (int)rintf(v.x * s), a1 = (int)rintf(v.y * s);
    int a2 = (int)rintf(v.z * s), a3 = (int)rintf(v.w * s);
    u32 wq = (u32)(a0 & 0xFF) | ((u32)(a1 & 0xFF) << 8) |
             ((u32)(a2 & 0xFF) << 16) | ((u32)(a3 & 0xFF) << 24);
    const int nt = n >> 5, c = n & 31, kc = kd >> 3, kb4 = kd & 7;
    Wq4[nt * 6144 + kc * 256 + c * 8 + kb4] = wq;
}

// ---------------------------------------------------------------------------
// Fused forward — r12's proven 2-phase pipelined schedule (bench 100.2 us)
// with ONE change: the A-phase is now fully COALESCED. Each wave processes
// its 32 rows one at a time: 64 lanes read 64 consecutive float4s (3 x 1 KB
// coalesced transactions per 3 KB row) instead of r12's lane-stride-3KB
// pattern (64 cache lines per instruction). Bits are combined via shfl_xor
// into m16 chunks and deposited in a 12 KB LDS panel; per-row psqt/popcount
// via wave reduce. Everything else (STAGE windows, COMPUTE, epilogue,
// (2,2) shell, grid 512 -> 2 blocks/CU) is r12 verbatim.
// ---------------------------------------------------------------------------
__global__ __launch_bounds__(256)
__attribute__((amdgpu_waves_per_eu(2, 2)))
void nnue_fwd(
    const float* __restrict__ x,       // [B][768], values in {0,1}
    const signed char* __restrict__ Wq2,
    const float* __restrict__ amax,
    const float* __restrict__ b_in,    // [1024]
    const float* __restrict__ W_h,     // [8][1024]
    const float* __restrict__ b_h,     // [8]
    const float* __restrict__ W_psqt,  // [768]
    float* __restrict__ out) {         // [B]

    __shared__ __align__(16) signed char bufs[2][24576];  // 48 KB
    __shared__ __align__(16) u16 abits16[128][2][24];     // 12 KB
    __shared__ int   bmeta[128];
    __shared__ float pmeta[128];

    const int t = threadIdx.x;
    const int l = t & 63, w = t >> 6;   // 4 waves = 4 row-strips
    const int cl = l & 31;              // row-in-strip / col-in-tile
    const int hi = l >> 5;              // K-half-of-fragment selector
    const size_t row0 = (size_t)blockIdx.x << 7;

    // STAGE(dst, c_, h_): copy chunk c_ (64 cols), K-half h_ (384 k) -> dst.
    // Wave w stages slabs j = w*6 .. w*6+5 (slab = 1 KB kc-slice of an nt).
#define STAGE(dst, c_, h_)                                                  \
    _Pragma("unroll")                                                       \
    for (int i = 0; i < 6; ++i) {                                           \
        int jj = w * 6 + i;                 /* 0..23 */                     \
        int ntl = jj >= 12 ? 1 : 0;                                         \
        int kcl = jj - ntl * 12;                                            \
        gld16(Wq2 + (size_t)(((c_) << 1) + ntl) * 24576                     \
                  + (size_t)((h_) * 12 + kcl) * 1024 + (l << 4),            \
              (signed char*)(dst) + jj * 1024);                             \
    }

    STAGE(bufs[0], 0, 0)        // stage 0 in flight under the A-phase

    // ---- A phase (coalesced): wave processes its 32 rows sequentially ---
    {
        const float4* pw = (const float4*)W_psqt;
#pragma unroll 2
        for (int rr = 0; rr < 32; ++rr) {
            const int row = (w << 5) + rr;
            const float4* xr = (const float4*)(x + (row0 + row) * 768);
            float ps = 0.0f;
            int cnt = 0;
            u32 mym[3];
#pragma unroll
            for (int i = 0; i < 3; ++i) {
                float4 f = xr[i * 64 + l];          // coalesced 1 KB / wave
                float4 p = pw[i * 64 + l];
                u32 nib = (__float_as_uint(f.x) >> 29)
                        | ((__float_as_uint(f.y) >> 29) << 1)
                        | ((__float_as_uint(f.z) >> 29) << 2)
                        | ((__float_as_uint(f.w) >> 29) << 3);
                ps = fmaf(f.x, p.x, ps); ps = fmaf(f.y, p.y, ps);
                ps = fmaf(f.z, p.z, ps); ps = fmaf(f.w, p.w, ps);
                cnt += __popc(nib);
                u32 v = nib << ((l & 3) << 2);
                v |= __shfl_xor(v, 1);
                v |= __shfl_xor(v, 2);              // 4 lanes -> m16
                mym[i] = v;
            }
            if ((l & 3) == 0) {
#pragma unroll
                for (int i = 0; i < 3; ++i) {
                    int q = (i << 4) + (l >> 2);    // 16-k chunk 0..47
                    abits16[row][q & 1][q >> 1] = (u16)mym[i];
                }
            }
#pragma unroll
            for (int d = 1; d < 64; d <<= 1) {
                ps  += __shfl_xor(ps, d);
                cnt += __shfl_xor(cnt, d);
            }
            if (l == 0) {
                bmeta[row] = (cnt - 1) >> 2;
                pmeta[row] = ps;
            }
        }
    }
    __syncthreads();            // panel+meta visible; stage 0 landed

    // ---- per-lane setup: gather Ab from the panel -----------------------
    const int r = (w << 5) + cl;
    u32 Ab[12];
    {
        const uint4* ap = (const uint4*)&abits16[r][hi][0];
        uint4 A0 = ap[0], A1 = ap[1], A2 = ap[2];
        Ab[0] = A0.x; Ab[1] = A0.y; Ab[2]  = A0.z; Ab[3]  = A0.w;
        Ab[4] = A1.x; Ab[5] = A1.y; Ab[6]  = A1.z; Ab[7]  = A1.w;
        Ab[8] = A2.x; Ab[9] = A2.y; Ab[10] = A2.z; Ab[11] = A2.w;
    }

    int whoff[16];
#pragma unroll
    for (int g = 0; g < 16; ++g) {
        int er = (w << 5) + (g & 3) + ((g >> 2) << 3) + (hi << 2);
        whoff[g] = bmeta[er] << 10;             // bucket * 1024
    }

    const float sc = amax[0] * (1.0f / 127.0f);
    float rs[16];
#pragma unroll
    for (int g = 0; g < 16; ++g) rs[g] = 0.0f;

#define COMPUTE(buf, h_)                                                    \
    {                                                                       \
        const signed char* bb = (const signed char*)(buf)                   \
                                + (cl << 5) + (hi << 4);                    \
        _Pragma("unroll")                                                   \
        for (int kc = 0; kc < 12; ++kc) {                                   \
            int ks = (h_) * 12 + kc;                                        \
            u32 pair = Ab[ks >> 1];                                         \
            asm volatile("" : "+v"(pair));      /* defeat hoist/CSE */      \
            u32 m = (ks & 1) ? (pair >> 16) : (pair & 0xFFFFu);             \
            i32x4 af;                                                       \
            af[0] = (int)(((m        & 0xFu) * 0x00204081u) & 0x01010101u); \
            af[1] = (int)((((m >> 4) & 0xFu) * 0x00204081u) & 0x01010101u); \
            af[2] = (int)((((m >> 8) & 0xFu) * 0x00204081u) & 0x01010101u); \
            af[3] = (int)((((m >> 12)      ) * 0x00204081u) & 0x01010101u); \
            i32x4 b0 = *(const i32x4*)(bb + (kc << 10));                    \
            i32x4 b1 = *(const i32x4*)(bb + 12288 + (kc << 10));            \
            acc0 = __builtin_amdgcn_mfma_i32_32x32x32_i8(af, b0, acc0, 0, 0, 0); \
            acc1 = __builtin_amdgcn_mfma_i32_32x32x32_i8(af, b1, acc1, 0, 0, 0); \
        }                                                                   \
    }

    // ---- main loop: 16 chunks x (2 K-half stages), 2 barriers/chunk -----
    for (int c = 0; c < 16; ++c) {
        i32x16 acc0 = {0,0,0,0,0,0,0,0,0,0,0,0,0,0,0,0};
        i32x16 acc1 = {0,0,0,0,0,0,0,0,0,0,0,0,0,0,0,0};

        // stage (c, half 1) into bufs[1]; compute (c, half 0) from bufs[0]
        STAGE(bufs[1], c, 1)
        COMPUTE(bufs[0], 0)
        __syncthreads();

        // stage (c+1, half 0) into bufs[0]; compute (c, half 1) from bufs[1]
        if (c < 15) STAGE(bufs[0], c + 1, 0)
        COMPUTE(bufs[1], 1)

        // fused epilogue (regs + L1-hot globals; covers the stage latency)
        const int col0 = (c << 6) + cl;
        const float bi0 = b_in[col0], bi1 = b_in[col0 + 32];
#pragma unroll
        for (int g = 0; g < 16; ++g) {
            float h0 = fminf(fmaxf(fmaf((float)acc0[g], sc, bi0), 0.f), 1.f);
            float h1 = fminf(fmaxf(fmaf((float)acc1[g], sc, bi1), 0.f), 1.f);
            rs[g] = fmaf(h0, W_h[whoff[g] + col0], rs[g]);
            rs[g] = fmaf(h1, W_h[whoff[g] + col0 + 32], rs[g]);
        }
        __syncthreads();
    }
#undef COMPUTE
#undef STAGE

    // ---- reduce over 32 col-lanes, write --------------------------------
#pragma unroll
    for (int g = 0; g < 16; ++g) {
#pragma unroll
        for (int d = 1; d < 32; d <<= 1) rs[g] += __shfl_xor(rs[g], d);
    }
    if (cl == 0) {
#pragma unroll
        for (int g = 0; g < 16; ++g) {
            int er = (w << 5) + (g & 3) + ((g >> 2) << 3) + (hi << 2);
            out[row0 + er] = rs[g] + pmeta[er] + b_h[whoff[g] >> 10];
        }
    }
}

extern "C" void kernel_launch(void* const* d_in, const int* in_sizes, int n_in,
                              void* d_out, int out_size, void* d_ws, size_t ws_size,
                              hipStream_t stream) {
    const float* x      = (const float*)d_in[0];
    const float* W_in   = (const float*)d_in[1];
    const float* b_in   = (const float*)d_in[2];
    const float* W_h    = (const float*)d_in[3];
    const float* b_h    = (const float*)d_in[4];
    const float* W_psqt = (const float*)d_in[5];
    float* out = (float*)d_out;

    float* amax = (float*)d_ws;
    float* part = (float*)((char*)d_ws + 64);
    signed char* Wq2 = (signed char*)d_ws + WQ_OFF;     // 768 KB

    amax_stage1<<<256, 256, 0, stream>>>(W_in, part);
    amax_stage2<<<1, 256, 0, stream>>>(part, amax);
    quant_k<<<1024, 192, 0, stream>>>(W_in, amax, (u32*)Wq2);

    int B = out_size;                   // 65536
    nnue_fwd<<<B / 128, 256, 0, stream>>>(x, Wq2, amax, b_in, W_h, b_h,
                                          W_psqt, out);
}

// Round 19
// 99.513 us; speedup vs baseline: 1.6509x; 1.0175x over previous
//
#include <hip/hip_runtime.h>

typedef unsigned int u32;
typedef unsigned short u16;
typedef int i32x4 __attribute__((ext_vector_type(4)));
typedef int i32x16 __attribute__((ext_vector_type(16)));

// ws layout (bytes):
//   [0..3]      amax (float)
//   [64..1087]  256 partial maxima (float)
//   [2048..]    Wq2: fragment-major i8 weights, 768 KB:
//               addr = nt*24576 + ks*1024 + col*32 + kb
//               (n = nt*32+col in [0,1024), k = ks*32+kb in [0,768))
#define WQ_OFF 2048

__device__ __forceinline__ void gld16(const void* g, void* l) {
    __builtin_amdgcn_global_load_lds(
        (const __attribute__((address_space(1))) void*)g,
        (__attribute__((address_space(3))) void*)l, 16, 0, 0);
}

// ---------------------------------------------------------------------------
// absmax two-stage tree (no atomics)
// ---------------------------------------------------------------------------
__global__ __launch_bounds__(256) void amax_stage1(const float* __restrict__ W,
                                                   float* __restrict__ part) {
    int t = blockIdx.x * 256 + threadIdx.x;
    float v = 0.0f;
#pragma unroll
    for (int k = 0; k < 12; ++k) v = fmaxf(v, fabsf(W[t + (k << 16)]));
#pragma unroll
    for (int d = 32; d >= 1; d >>= 1) v = fmaxf(v, __shfl_xor(v, d));
    __shared__ float sm[4];
    if ((threadIdx.x & 63) == 0) sm[threadIdx.x >> 6] = v;
    __syncthreads();
    if (threadIdx.x == 0)
        part[blockIdx.x] = fmaxf(fmaxf(sm[0], sm[1]), fmaxf(sm[2], sm[3]));
}

__global__ __launch_bounds__(256) void amax_stage2(const float* __restrict__ part,
                                                   float* __restrict__ amax) {
    float v = part[threadIdx.x];
#pragma unroll
    for (int d = 32; d >= 1; d >>= 1) v = fmaxf(v, __shfl_xor(v, d));
    __shared__ float sm[4];
    if ((threadIdx.x & 63) == 0) sm[threadIdx.x >> 6] = v;
    __syncthreads();
    if (threadIdx.x == 0)
        amax[0] = fmaxf(fmaxf(sm[0], sm[1]), fmaxf(sm[2], sm[3]));
}

// ---------------------------------------------------------------------------
// quantize W_in [1024][768] f32 -> Wq2 fragment-major i8 (validated r9-r18)
// ---------------------------------------------------------------------------
__global__ __launch_bounds__(192) void quant_k(const float* __restrict__ W,
                                               const float* __restrict__ amax,
                                               u32* __restrict__ Wq4) {
    const int n = blockIdx.x, kd = threadIdx.x;     // kd: dword index 0..191
    float s = 127.0f / amax[0];
    float4 v = ((const float4*)(W + n * 768))[kd];
    int a0 = (int)rintf(v.x * s), a1 = (int)rintf(v.y * s);
    int a2 = (int)rintf(v.z * s), a3 = (int)rintf(v.w * s);
    u32 wq = (u32)(a0 & 0xFF) | ((u32)(a1 & 0xFF) << 8) |
             ((u32)(a2 & 0xFF) << 16) | ((u32)(a3 & 0xFF) << 24);
    const int nt = n >> 5, c = n & 31, kc = kd >> 3, kb4 = kd & 7;
    Wq4[nt * 6144 + kc * 256 + c * 8 + kb4] = wq;
}

// ---------------------------------------------------------------------------
// Fused forward — champion (r12/r18) schedule with the af-expansion HOISTED.
// At the (2,2) shell's 256-reg unified budget, all 24 expanded A-fragments
// (96 VGPRs) fit alongside acc/rs/whoff (~220 total), so the bit->i8
// expansion runs ONCE per lane instead of once per chunk (16x redundancy
// removed, ~60% of in-loop VALU). COMPUTE is now pure ds_read + MFMA.
// Everything else identical to r18: coalesced A-phase, 2-phase pipelined
// 24 KB windows, stage-before-compute, 2 barriers/chunk, grid 512.
// ---------------------------------------------------------------------------
__global__ __launch_bounds__(256)
__attribute__((amdgpu_waves_per_eu(2, 2)))
void nnue_fwd(
    const float* __restrict__ x,       // [B][768], values in {0,1}
    const signed char* __restrict__ Wq2,
    const float* __restrict__ amax,
    const float* __restrict__ b_in,    // [1024]
    const float* __restrict__ W_h,     // [8][1024]
    const float* __restrict__ b_h,     // [8]
    const float* __restrict__ W_psqt,  // [768]
    float* __restrict__ out) {         // [B]

    __shared__ __align__(16) signed char bufs[2][24576];  // 48 KB
    __shared__ __align__(16) u16 abits16[128][2][24];     // 12 KB
    __shared__ int   bmeta[128];
    __shared__ float pmeta[128];

    const int t = threadIdx.x;
    const int l = t & 63, w = t >> 6;   // 4 waves = 4 row-strips
    const int cl = l & 31;              // row-in-strip / col-in-tile
    const int hi = l >> 5;              // K-half-of-fragment selector
    const size_t row0 = (size_t)blockIdx.x << 7;

    // STAGE(dst, c_, h_): copy chunk c_ (64 cols), K-half h_ (384 k) -> dst.
#define STAGE(dst, c_, h_)                                                  \
    _Pragma("unroll")                                                       \
    for (int i = 0; i < 6; ++i) {                                           \
        int jj = w * 6 + i;                 /* 0..23 */                     \
        int ntl = jj >= 12 ? 1 : 0;                                         \
        int kcl = jj - ntl * 12;                                            \
        gld16(Wq2 + (size_t)(((c_) << 1) + ntl) * 24576                     \
                  + (size_t)((h_) * 12 + kcl) * 1024 + (l << 4),            \
              (signed char*)(dst) + jj * 1024);                             \
    }

    STAGE(bufs[0], 0, 0)        // stage 0 in flight under the A-phase

    // ---- A phase (coalesced): wave processes its 32 rows sequentially ---
    {
        const float4* pw = (const float4*)W_psqt;
#pragma unroll 2
        for (int rr = 0; rr < 32; ++rr) {
            const int row = (w << 5) + rr;
            const float4* xr = (const float4*)(x + (row0 + row) * 768);
            float ps = 0.0f;
            int cnt = 0;
            u32 mym[3];
#pragma unroll
            for (int i = 0; i < 3; ++i) {
                float4 f = xr[i * 64 + l];          // coalesced 1 KB / wave
                float4 p = pw[i * 64 + l];
                u32 nib = (__float_as_uint(f.x) >> 29)
                        | ((__float_as_uint(f.y) >> 29) << 1)
                        | ((__float_as_uint(f.z) >> 29) << 2)
                        | ((__float_as_uint(f.w) >> 29) << 3);
                ps = fmaf(f.x, p.x, ps); ps = fmaf(f.y, p.y, ps);
                ps = fmaf(f.z, p.z, ps); ps = fmaf(f.w, p.w, ps);
                cnt += __popc(nib);
                u32 v = nib << ((l & 3) << 2);
                v |= __shfl_xor(v, 1);
                v |= __shfl_xor(v, 2);              // 4 lanes -> m16
                mym[i] = v;
            }
            if ((l & 3) == 0) {
#pragma unroll
                for (int i = 0; i < 3; ++i) {
                    int q = (i << 4) + (l >> 2);    // 16-k chunk 0..47
                    abits16[row][q & 1][q >> 1] = (u16)mym[i];
                }
            }
#pragma unroll
            for (int d = 1; d < 64; d <<= 1) {
                ps  += __shfl_xor(ps, d);
                cnt += __shfl_xor(cnt, d);
            }
            if (l == 0) {
                bmeta[row] = (cnt - 1) >> 2;
                pmeta[row] = ps;
            }
        }
    }
    __syncthreads();            // panel+meta visible; stage 0 landed

    // ---- per-lane setup: gather Ab, expand ALL 24 fragments ONCE --------
    const int r = (w << 5) + cl;
    i32x4 afr[24];              // 96 VGPRs, live across the whole main loop
    {
        const uint4* ap = (const uint4*)&abits16[r][hi][0];
        uint4 A0 = ap[0], A1 = ap[1], A2 = ap[2];
        u32 Ab[12] = {A0.x, A0.y, A0.z, A0.w,
                      A1.x, A1.y, A1.z, A1.w,
                      A2.x, A2.y, A2.z, A2.w};
#pragma unroll
        for (int ks = 0; ks < 24; ++ks) {
            u32 pair = Ab[ks >> 1];
            u32 m = (ks & 1) ? (pair >> 16) : (pair & 0xFFFFu);
            afr[ks][0] = (int)(((m         & 0xFu) * 0x00204081u) & 0x01010101u);
            afr[ks][1] = (int)((((m >> 4)  & 0xFu) * 0x00204081u) & 0x01010101u);
            afr[ks][2] = (int)((((m >> 8)  & 0xFu) * 0x00204081u) & 0x01010101u);
            afr[ks][3] = (int)((((m >> 12)       ) * 0x00204081u) & 0x01010101u);
        }
    }

    int whoff[16];
#pragma unroll
    for (int g = 0; g < 16; ++g) {
        int er = (w << 5) + (g & 3) + ((g >> 2) << 3) + (hi << 2);
        whoff[g] = bmeta[er] << 10;             // bucket * 1024
    }

    const float sc = amax[0] * (1.0f / 127.0f);
    float rs[16];
#pragma unroll
    for (int g = 0; g < 16; ++g) rs[g] = 0.0f;

#define COMPUTE(buf, h_)                                                    \
    {                                                                       \
        const signed char* bb = (const signed char*)(buf)                   \
                                + (cl << 5) + (hi << 4);                    \
        _Pragma("unroll")                                                   \
        for (int kc = 0; kc < 12; ++kc) {                                   \
            int ks = (h_) * 12 + kc;                                        \
            i32x4 b0 = *(const i32x4*)(bb + (kc << 10));                    \
            i32x4 b1 = *(const i32x4*)(bb + 12288 + (kc << 10));            \
            acc0 = __builtin_amdgcn_mfma_i32_32x32x32_i8(afr[ks], b0, acc0, 0, 0, 0); \
            acc1 = __builtin_amdgcn_mfma_i32_32x32x32_i8(afr[ks], b1, acc1, 0, 0, 0); \
        }                                                                   \
    }

    // ---- main loop: 16 chunks x (2 K-half stages), 2 barriers/chunk -----
    for (int c = 0; c < 16; ++c) {
        i32x16 acc0 = {0,0,0,0,0,0,0,0,0,0,0,0,0,0,0,0};
        i32x16 acc1 = {0,0,0,0,0,0,0,0,0,0,0,0,0,0,0,0};

        // stage (c, half 1) into bufs[1]; compute (c, half 0) from bufs[0]
        STAGE(bufs[1], c, 1)
        COMPUTE(bufs[0], 0)
        __syncthreads();

        // stage (c+1, half 0) into bufs[0]; compute (c, half 1) from bufs[1]
        if (c < 15) STAGE(bufs[0], c + 1, 0)
        COMPUTE(bufs[1], 1)

        // fused epilogue (regs + L1-hot globals; covers the stage latency)
        const int col0 = (c << 6) + cl;
        const float bi0 = b_in[col0], bi1 = b_in[col0 + 32];
#pragma unroll
        for (int g = 0; g < 16; ++g) {
            float h0 = fminf(fmaxf(fmaf((float)acc0[g], sc, bi0), 0.f), 1.f);
            float h1 = fminf(fmaxf(fmaf((float)acc1[g], sc, bi1), 0.f), 1.f);
            rs[g] = fmaf(h0, W_h[whoff[g] + col0], rs[g]);
            rs[g] = fmaf(h1, W_h[whoff[g] + col0 + 32], rs[g]);
        }
        __syncthreads();
    }
#undef COMPUTE
#undef STAGE

    // ---- reduce over 32 col-lanes, write --------------------------------
#pragma unroll
    for (int g = 0; g < 16; ++g) {
#pragma unroll
        for (int d = 1; d < 32; d <<= 1) rs[g] += __shfl_xor(rs[g], d);
    }
    if (cl == 0) {
#pragma unroll
        for (int g = 0; g < 16; ++g) {
            int er = (w << 5) + (g & 3) + ((g >> 2) << 3) + (hi << 2);
            out[row0 + er] = rs[g] + pmeta[er] + b_h[whoff[g] >> 10];
        }
    }
}

extern "C" void kernel_launch(void* const* d_in, const int* in_sizes, int n_in,
                              void* d_out, int out_size, void* d_ws, size_t ws_size,
                              hipStream_t stream) {
    const float* x      = (const float*)d_in[0];
    const float* W_in   = (const float*)d_in[1];
    const float* b_in   = (const float*)d_in[2];
    const float* W_h    = (const float*)d_in[3];
    const float* b_h    = (const float*)d_in[4];
    const float* W_psqt = (const float*)d_in[5];
    float* out = (float*)d_out;

    float* amax = (float*)d_ws;
    float* part = (float*)((char*)d_ws + 64);
    signed char* Wq2 = (signed char*)d_ws + WQ_OFF;     // 768 KB

    amax_stage1<<<256, 256, 0, stream>>>(W_in, part);
    amax_stage2<<<1, 256, 0, stream>>>(part, amax);
    quant_k<<<1024, 192, 0, stream>>>(W_in, amax, (u32*)Wq2);

    int B = out_size;                   // 65536
    nnue_fwd<<<B / 128, 256, 0, stream>>>(x, Wq2, amax, b_in, W_h, b_h,
                                          W_psqt, out);
}